// Round 1
// baseline (9812.903 us; speedup 1.0000x reference)
//
#include <hip/hip_runtime.h>
#include <math.h>

#define BB 64
#define TT 128
#define SS 256
#define HHH 1024

__device__ __forceinline__ float sigmoidf_(float x) { return 1.0f / (1.0f + expf(-x)); }

// ---------------------------------------------------------------------------
// C[m,n] = sum_k A[m,k] * Bm[n,k]   (B stored row-major [N,K], i.e. A @ B^T)
// Optional epilogue: + bias0[n] + bias1[n], tanh.
// Batched via blockIdx.z with element strides sA/sB/sC.
// ---------------------------------------------------------------------------
template <int BM, int BN, int TM, int TN, bool BIAS2, bool TANH_OUT>
__global__ __launch_bounds__(256) void gemm_bt(
    const float* __restrict__ A, const float* __restrict__ Bm, float* __restrict__ C,
    const float* __restrict__ bias0, const float* __restrict__ bias1,
    int M, int N, int K, long sA, long sB, long sC)
{
    constexpr int BK = 16;
    __shared__ float As[BK][BM + 1];
    __shared__ float Bs[BK][BN + 1];
    const int z = blockIdx.z;
    A += (long)z * sA; Bm += (long)z * sB; C += (long)z * sC;
    const int bm = blockIdx.y * BM, bn = blockIdx.x * BN;
    const int tid = threadIdx.x;
    constexpr int TC = BN / TN;
    const int tc = tid % TC, tr = tid / TC;
    float acc[TM][TN] = {};
    for (int k0 = 0; k0 < K; k0 += BK) {
        for (int i = tid; i < BM * 4; i += 256) {
            int m = i >> 2, k4 = (i & 3) << 2;
            float4 v = *(const float4*)(A + (long)(bm + m) * K + k0 + k4);
            As[k4][m] = v.x; As[k4 + 1][m] = v.y; As[k4 + 2][m] = v.z; As[k4 + 3][m] = v.w;
        }
        for (int i = tid; i < BN * 4; i += 256) {
            int n = i >> 2, k4 = (i & 3) << 2;
            float4 v = *(const float4*)(Bm + (long)(bn + n) * K + k0 + k4);
            Bs[k4][n] = v.x; Bs[k4 + 1][n] = v.y; Bs[k4 + 2][n] = v.z; Bs[k4 + 3][n] = v.w;
        }
        __syncthreads();
#pragma unroll
        for (int kk = 0; kk < BK; ++kk) {
            float a[TM], b[TN];
#pragma unroll
            for (int i = 0; i < TM; i++) a[i] = As[kk][tr * TM + i];
#pragma unroll
            for (int j = 0; j < TN; j++) b[j] = Bs[kk][tc * TN + j];
#pragma unroll
            for (int i = 0; i < TM; i++)
#pragma unroll
                for (int j = 0; j < TN; j++) acc[i][j] += a[i] * b[j];
        }
        __syncthreads();
    }
#pragma unroll
    for (int i = 0; i < TM; i++) {
        int m = bm + tr * TM + i;
#pragma unroll
        for (int j = 0; j < TN; j++) {
            int n = bn + tc * TN + j;
            float v = acc[i][j];
            if (BIAS2) v += bias0[n] + bias1[n];
            if (TANH_OUT) v = tanhf(v);
            C[(long)m * N + n] = v;
        }
    }
}

// ---------------------------------------------------------------------------
// C[m,n] = sum_k A[m,k] * Bm[k,n]   (B row-major [K,N]) — for context = attn @ ctx
// ---------------------------------------------------------------------------
template <int BM, int BN, int TM, int TN>
__global__ __launch_bounds__(256) void gemm_bn(
    const float* __restrict__ A, const float* __restrict__ Bm, float* __restrict__ C,
    int M, int N, int K, long sA, long sB, long sC)
{
    constexpr int BK = 16;
    __shared__ float As[BK][BM + 1];
    __shared__ float Bs[BK][BN + 1];
    const int z = blockIdx.z;
    A += (long)z * sA; Bm += (long)z * sB; C += (long)z * sC;
    const int bm = blockIdx.y * BM, bn = blockIdx.x * BN;
    const int tid = threadIdx.x;
    constexpr int TC = BN / TN;
    const int tc = tid % TC, tr = tid / TC;
    float acc[TM][TN] = {};
    for (int k0 = 0; k0 < K; k0 += BK) {
        for (int i = tid; i < BM * 4; i += 256) {
            int m = i >> 2, k4 = (i & 3) << 2;
            float4 v = *(const float4*)(A + (long)(bm + m) * K + k0 + k4);
            As[k4][m] = v.x; As[k4 + 1][m] = v.y; As[k4 + 2][m] = v.z; As[k4 + 3][m] = v.w;
        }
        for (int i = tid; i < BK * (BN / 4); i += 256) {
            int k = i / (BN / 4), n4 = (i % (BN / 4)) * 4;
            float4 v = *(const float4*)(Bm + (long)(k0 + k) * N + bn + n4);
            Bs[k][n4] = v.x; Bs[k][n4 + 1] = v.y; Bs[k][n4 + 2] = v.z; Bs[k][n4 + 3] = v.w;
        }
        __syncthreads();
#pragma unroll
        for (int kk = 0; kk < BK; ++kk) {
            float a[TM], b[TN];
#pragma unroll
            for (int i = 0; i < TM; i++) a[i] = As[kk][tr * TM + i];
#pragma unroll
            for (int j = 0; j < TN; j++) b[j] = Bs[kk][tc * TN + j];
#pragma unroll
            for (int i = 0; i < TM; i++)
#pragma unroll
                for (int j = 0; j < TN; j++) acc[i][j] += a[i] * b[j];
        }
        __syncthreads();
    }
#pragma unroll
    for (int i = 0; i < TM; i++) {
        int m = bm + tr * TM + i;
#pragma unroll
        for (int j = 0; j < TN; j++) {
            int n = bn + tc * TN + j;
            C[(long)m * N + n] = acc[i][j];
        }
    }
}

// ---------------------------------------------------------------------------
// h_tilde = tanh([context, lstm_out] @ W_out^T)   K=2048 split 1024/1024
// ---------------------------------------------------------------------------
template <int BM, int BN, int TM, int TN>
__global__ __launch_bounds__(256) void gemm_concat_tanh(
    const float* __restrict__ A0, const float* __restrict__ A1,
    const float* __restrict__ Bm, float* __restrict__ C, int M, int N)
{
    constexpr int BK = 16;
    constexpr int K = 2048;
    __shared__ float As[BK][BM + 1];
    __shared__ float Bs[BK][BN + 1];
    const int bm = blockIdx.y * BM, bn = blockIdx.x * BN;
    const int tid = threadIdx.x;
    constexpr int TC = BN / TN;
    const int tc = tid % TC, tr = tid / TC;
    float acc[TM][TN] = {};
    for (int k0 = 0; k0 < K; k0 += BK) {
        const float* Ap = (k0 < 1024) ? A0 : A1;
        const int kb = (k0 < 1024) ? k0 : (k0 - 1024);
        for (int i = tid; i < BM * 4; i += 256) {
            int m = i >> 2, k4 = (i & 3) << 2;
            float4 v = *(const float4*)(Ap + (long)(bm + m) * 1024 + kb + k4);
            As[k4][m] = v.x; As[k4 + 1][m] = v.y; As[k4 + 2][m] = v.z; As[k4 + 3][m] = v.w;
        }
        for (int i = tid; i < BN * 4; i += 256) {
            int n = i >> 2, k4 = (i & 3) << 2;
            float4 v = *(const float4*)(Bm + (long)(bn + n) * 2048 + k0 + k4);
            Bs[k4][n] = v.x; Bs[k4 + 1][n] = v.y; Bs[k4 + 2][n] = v.z; Bs[k4 + 3][n] = v.w;
        }
        __syncthreads();
#pragma unroll
        for (int kk = 0; kk < BK; ++kk) {
            float a[TM], b[TN];
#pragma unroll
            for (int i = 0; i < TM; i++) a[i] = As[kk][tr * TM + i];
#pragma unroll
            for (int j = 0; j < TN; j++) b[j] = Bs[kk][tc * TN + j];
#pragma unroll
            for (int i = 0; i < TM; i++)
#pragma unroll
                for (int j = 0; j < TN; j++) acc[i][j] += a[i] * b[j];
        }
        __syncthreads();
    }
#pragma unroll
    for (int i = 0; i < TM; i++) {
        int m = bm + tr * TM + i;
#pragma unroll
        for (int j = 0; j < TN; j++) {
            int n = bn + tc * TN + j;
            C[(long)m * N + n] = tanhf(acc[i][j]);
        }
    }
}

// ---------------------------------------------------------------------------
// One LSTM timestep, fused gates-GEMM + activation + state update.
// Block = 256 thr, owns j-chunk of 8 hidden units for ALL 64 batches and
// all 4 gates (N-tile = 32 cols: [i(8) f(8) g(8) o(8)]).
// h double-buffered across launches (h_in read-only, h_out written).
// c updated in place (each (b,j) owned by exactly one block).
// ---------------------------------------------------------------------------
__global__ __launch_bounds__(256) void lstm_step(
    const float* __restrict__ xg, const float* __restrict__ W_hh,
    const float* __restrict__ h_in, float* __restrict__ h_out,
    float* __restrict__ c, float* __restrict__ lstm_out, int t)
{
    constexpr int BK = 16;
    __shared__ float As[BK][65];
    __shared__ float Bs[BK][33];
    __shared__ float gsm[64][33];
    const int j0 = blockIdx.x * 8;
    const int tid = threadIdx.x;
    const int tc = tid & 15, tr = tid >> 4;  // 16x16 threads, TM=4 (b), TN=2 (n)
    float acc[4][2] = {};
    for (int k0 = 0; k0 < 1024; k0 += BK) {
        for (int i = tid; i < 64 * 4; i += 256) {
            int m = i >> 2, k4 = (i & 3) << 2;
            float4 v = *(const float4*)(h_in + (long)m * 1024 + k0 + k4);
            As[k4][m] = v.x; As[k4 + 1][m] = v.y; As[k4 + 2][m] = v.z; As[k4 + 3][m] = v.w;
        }
        for (int i = tid; i < 32 * 4; i += 256) {
            int n = i >> 2, k4 = (i & 3) << 2;
            int row = (n >> 3) * 1024 + j0 + (n & 7);
            float4 v = *(const float4*)(W_hh + (long)row * 1024 + k0 + k4);
            Bs[k4][n] = v.x; Bs[k4 + 1][n] = v.y; Bs[k4 + 2][n] = v.z; Bs[k4 + 3][n] = v.w;
        }
        __syncthreads();
#pragma unroll
        for (int kk = 0; kk < BK; ++kk) {
            float a[4], b[2];
#pragma unroll
            for (int i = 0; i < 4; i++) a[i] = As[kk][tr * 4 + i];
            b[0] = Bs[kk][tc * 2]; b[1] = Bs[kk][tc * 2 + 1];
#pragma unroll
            for (int i = 0; i < 4; i++) {
                acc[i][0] += a[i] * b[0];
                acc[i][1] += a[i] * b[1];
            }
        }
        __syncthreads();
    }
#pragma unroll
    for (int i = 0; i < 4; i++) {
        gsm[tr * 4 + i][tc * 2] = acc[i][0];
        gsm[tr * 4 + i][tc * 2 + 1] = acc[i][1];
    }
    __syncthreads();
    for (int p = tid; p < 512; p += 256) {
        int b = p >> 3, jj = p & 7, j = j0 + jj;
        long xb = ((long)b * TT + t) * 4096;
        float gi = gsm[b][jj] + xg[xb + j];
        float gf = gsm[b][8 + jj] + xg[xb + 1024 + j];
        float gg = gsm[b][16 + jj] + xg[xb + 2048 + j];
        float go = gsm[b][24 + jj] + xg[xb + 3072 + j];
        float ii = sigmoidf_(gi), ff = sigmoidf_(gf), g2 = tanhf(gg), oo = sigmoidf_(go);
        long ci = (long)b * 1024 + j;
        float cn = ff * c[ci] + ii * g2;
        float hn = oo * tanhf(cn);
        c[ci] = cn;
        h_out[ci] = hn;
        lstm_out[((long)b * TT + t) * 1024 + j] = hn;
    }
}

// ---------------------------------------------------------------------------
// Masked softmax over S=256, in place. One block per (b,t) row.
// ---------------------------------------------------------------------------
__global__ __launch_bounds__(256) void softmax_mask(
    float* __restrict__ attn, const int* __restrict__ src_len)
{
    __shared__ float red[4];
    const int b = blockIdx.y, t = blockIdx.x, s = threadIdx.x;
    float* row = attn + ((long)b * TT + t) * SS;
    const int L = src_len[b];
    float v = (s < L) ? row[s] : -INFINITY;
    float m = v;
#pragma unroll
    for (int o = 32; o >= 1; o >>= 1) m = fmaxf(m, __shfl_xor(m, o));
    if ((s & 63) == 0) red[s >> 6] = m;
    __syncthreads();
    m = fmaxf(fmaxf(red[0], red[1]), fmaxf(red[2], red[3]));
    __syncthreads();
    float e = (s < L) ? expf(v - m) : 0.0f;
    float sum = e;
#pragma unroll
    for (int o = 32; o >= 1; o >>= 1) sum += __shfl_xor(sum, o);
    if ((s & 63) == 0) red[s >> 6] = sum;
    __syncthreads();
    sum = red[0] + red[1] + red[2] + red[3];
    row[s] = e / sum;
}

// ---------------------------------------------------------------------------
extern "C" void kernel_launch(void* const* d_in, const int* in_sizes, int n_in,
                              void* d_out, int out_size, void* d_ws, size_t ws_size,
                              hipStream_t stream)
{
    const float* trg_emb = (const float*)d_in[0];
    const float* h0      = (const float*)d_in[1];
    const float* c0      = (const float*)d_in[2];
    const float* ctx     = (const float*)d_in[3];
    const int*   src_len = (const int*)d_in[4];
    const float* W_ih    = (const float*)d_in[5];
    const float* W_hh    = (const float*)d_in[6];
    const float* b_ih    = (const float*)d_in[7];
    const float* b_hh    = (const float*)d_in[8];
    const float* W_in    = (const float*)d_in[9];
    const float* W_out   = (const float*)d_in[10];

    float* out = (float*)d_out;
    float* h_tilde = out;                          // [B,T,H]
    float* hT = out + (size_t)BB * TT * HHH;       // [1,B,H]
    float* cT = hT + (size_t)BB * HHH;             // [1,B,H] — used as running c

    float* ws = (float*)d_ws;
    float* xg       = ws;                          // [B,T,4H] = 33,554,432 f
    float* lstm_out = ws + (size_t)33554432;       // [B,T,H]  =  8,388,608 f
    float* hb0      = ws + (size_t)41943040;       // [B,H]
    float* hb1      = hb0 + (size_t)BB * HHH;      // [B,H]
    // reuse xg region after the scan:
    float* q      = ws;                            // [B,T,H]
    float* attn   = ws + (size_t)8388608;          // [B,T,S]
    float* ctxout = ws + (size_t)10485760;         // [B,T,H]

    // init running states
    hipMemcpyAsync(cT, c0, (size_t)BB * HHH * 4, hipMemcpyDeviceToDevice, stream);
    hipMemcpyAsync(hb0, h0, (size_t)BB * HHH * 4, hipMemcpyDeviceToDevice, stream);

    // x_gates = trg_emb @ W_ih^T + b_ih + b_hh
    gemm_bt<64, 64, 4, 4, true, false><<<dim3(64, 128, 1), 256, 0, stream>>>(
        trg_emb, W_ih, xg, b_ih, b_hh, BB * TT, 4 * HHH, 1024, 0, 0, 0);

    // LSTM scan (h ping-pong across launches; c in place)
    for (int t = 0; t < TT; ++t) {
        const float* hi = (t & 1) ? hb1 : hb0;
        float* ho = (t & 1) ? hb0 : hb1;
        lstm_step<<<dim3(128, 1, 1), 256, 0, stream>>>(xg, W_hh, hi, ho, cT, lstm_out, t);
    }
    hipMemcpyAsync(hT, hb0, (size_t)BB * HHH * 4, hipMemcpyDeviceToDevice, stream);

    // q = lstm_out @ W_in^T
    gemm_bt<64, 64, 4, 4, false, false><<<dim3(16, 128, 1), 256, 0, stream>>>(
        lstm_out, W_in, q, nullptr, nullptr, BB * TT, HHH, HHH, 0, 0, 0);

    // scores[b] = q[b] @ ctx[b]^T  (batched)
    gemm_bt<64, 64, 4, 4, false, false><<<dim3(4, 2, 64), 256, 0, stream>>>(
        q, ctx, attn, nullptr, nullptr, TT, SS, HHH,
        (long)TT * HHH, (long)SS * HHH, (long)TT * SS);

    // masked softmax in place
    softmax_mask<<<dim3(TT, BB, 1), 256, 0, stream>>>(attn, src_len);

    // context[b] = attn[b] @ ctx[b]
    gemm_bn<64, 64, 4, 4><<<dim3(16, 2, 64), 256, 0, stream>>>(
        attn, ctx, ctxout, TT, HHH, SS,
        (long)TT * SS, (long)SS * HHH, (long)TT * HHH);

    // h_tilde = tanh([context, lstm_out] @ W_out^T)
    gemm_concat_tanh<64, 64, 4, 4><<<dim3(16, 128, 1), 256, 0, stream>>>(
        ctxout, lstm_out, W_out, h_tilde, BB * TT, HHH);
}

// Round 3
// 2457.911 us; speedup vs baseline: 3.9924x; 3.9924x over previous
//
#include <hip/hip_runtime.h>
#include <math.h>

#define BB 64
#define TT 128
#define SS 256
#define HHH 1024

typedef unsigned short u16;
typedef __bf16 bf16x8 __attribute__((ext_vector_type(8)));
typedef float f32x4 __attribute__((ext_vector_type(4)));
typedef u16 u16x8 __attribute__((ext_vector_type(8)));

__device__ __forceinline__ float sigmoidf_(float x) { return 1.0f / (1.0f + expf(-x)); }
__device__ __forceinline__ u16 f2bf(float f) {
    __bf16 h = (__bf16)f;
    return __builtin_bit_cast(u16, h);
}
__device__ __forceinline__ float b2f(u16 u) {
    return __builtin_bit_cast(float, (unsigned)u << 16);
}
template <typename OT>
__device__ __forceinline__ void stout(OT* p, float v) {
    if constexpr (sizeof(OT) == 2) *p = f2bf(v); else *p = v;
}

// ---------------------------------------------------------------------------
// fp32 → bf16 elementwise (n divisible by 2048; grid = n/2048, 256 thr)
// ---------------------------------------------------------------------------
__global__ __launch_bounds__(256) void f32_to_bf16(const float* __restrict__ in,
                                                   u16* __restrict__ out, long n) {
    long i = ((long)blockIdx.x * 256 + threadIdx.x) * 8;
    float4 a = *(const float4*)(in + i);
    float4 b = *(const float4*)(in + i + 4);
    u16x8 o;
    o[0] = f2bf(a.x); o[1] = f2bf(a.y); o[2] = f2bf(a.z); o[3] = f2bf(a.w);
    o[4] = f2bf(b.x); o[5] = f2bf(b.y); o[6] = f2bf(b.z); o[7] = f2bf(b.w);
    *(u16x8*)(out + i) = o;
}

// ---------------------------------------------------------------------------
// MFMA bf16 GEMM: C[m,n] = sum_k A[m,k]*B[n,k]  (both row-major, K contiguous)
// A optionally split at KA0 into A0/A1 (concat along K). 128x128 tile, BK=32,
// 256 thr = 4 waves (2x2 quadrants of 64x64), mfma_f32_16x16x32_bf16.
// XGT mode: logical A-row r = t*64+b (phys row = (r&63)*128 + (r>>6));
//   C written fp32-transposed to xgt[t][col][b] with (b_ih+b_hh)[col] added.
//   Eliminates intermediate bf16 rounding of the gate pre-activations.
// ---------------------------------------------------------------------------
template <bool TANH, bool XGT, typename OT>
__global__ __launch_bounds__(256) void gemm_mfma_bt(
    const u16* __restrict__ A0, const u16* __restrict__ A1,
    const u16* __restrict__ B, OT* __restrict__ C,
    int M, int N, int K, int KA0,
    const float* __restrict__ bias0, const float* __restrict__ bias1)
{
    __shared__ uint4 As4[512];
    __shared__ uint4 Bs4[512];
    u16* As = (u16*)As4;
    u16* Bs = (u16*)Bs4;
    const int tid = threadIdx.x;
    const int l = tid & 63;
    const int w = tid >> 6;
    const int wm = w >> 1, wn = w & 1;
    const int tc = l & 15, tr8 = (l >> 4) << 3;
    const int m0 = blockIdx.y << 7, n0 = blockIdx.x << 7;
    f32x4 acc[4][4] = {};

    for (int k0 = 0; k0 < K; k0 += 32) {
        const u16* Ap = (k0 < KA0) ? A0 : A1;
        const int koff = (k0 < KA0) ? k0 : k0 - KA0;
#pragma unroll
        for (int r = 0; r < 2; ++r) {
            int u = tid + (r << 8);
            int row = u >> 2, q = u & 3;
            size_t arow;
            if (XGT) {
                int rr = m0 + row;
                arow = (size_t)((rr & 63) * 128 + (rr >> 6));
            } else {
                arow = (size_t)(m0 + row);
            }
            As4[u] = *(const uint4*)(Ap + arow * KA0 + koff + (q << 3));
            Bs4[u] = *(const uint4*)(B + (size_t)(n0 + row) * K + k0 + (q << 3));
        }
        __syncthreads();
        bf16x8 bfr[4];
#pragma unroll
        for (int j = 0; j < 4; ++j)
            bfr[j] = *(const bf16x8*)(Bs + ((wn << 6) + (j << 4) + tc) * 32 + tr8);
#pragma unroll
        for (int i = 0; i < 4; ++i) {
            bf16x8 af = *(const bf16x8*)(As + ((wm << 6) + (i << 4) + tc) * 32 + tr8);
#pragma unroll
            for (int j = 0; j < 4; ++j)
                acc[i][j] = __builtin_amdgcn_mfma_f32_16x16x32_bf16(af, bfr[j], acc[i][j], 0, 0, 0);
        }
        __syncthreads();
    }
#pragma unroll
    for (int j = 0; j < 4; ++j) {
        const int col = n0 + (wn << 6) + (j << 4) + tc;
        const float bias = XGT ? (bias0[col] + bias1[col]) : 0.0f;
#pragma unroll
        for (int i = 0; i < 4; ++i) {
#pragma unroll
            for (int v = 0; v < 4; ++v) {
                int r = m0 + (wm << 6) + (i << 4) + ((l >> 4) << 2) + v;
                float val = acc[i][j][v];
                if (XGT) {
                    ((float*)C)[(size_t)(r >> 6) * 262144 + (size_t)col * 64 + (r & 63)] = val + bias;
                } else {
                    if (TANH) val = tanhf(val);
                    stout(&C[(size_t)r * N + col], val);
                }
            }
        }
    }
}

// ---------------------------------------------------------------------------
// One LSTM timestep. 256 blocks x 256 thr. Block owns 4 hidden units j
// (16 W_hh rows: 4 gates x 4 j) for all 64 batches. 4 waves = 4 private
// K-quarters (no intra-K-loop barriers); register-prefetched staging;
// one barrier before reduce + fused activations/state update.
// fp32 math throughout; h kept fp32; xgt read fp32; lstm_out written bf16.
// ---------------------------------------------------------------------------
__global__ __launch_bounds__(256) void lstm_step2(
    const float* __restrict__ xgt, const float* __restrict__ W_hh,
    const float* __restrict__ h_in, float* __restrict__ h_out,
    float* __restrict__ c, u16* __restrict__ lstm16, int t)
{
    __shared__ float hs[4][32][68];
    __shared__ float wsm[4][32][20];
    __shared__ float red[4][1032];
    const int bid = blockIdx.x;
    const int j0 = (((bid & 7) << 5) | (bid >> 3)) << 2;   // XCD-grouped j
    const int tid = threadIdx.x;
    const int kg = tid >> 6;          // wave id = K-quarter
    const int l = tid & 63;
    const int tr = l >> 4, tc = l & 15;
    const int kbase = kg << 8;
    const int hb = l >> 3;            // 0..7
    const int kq = l & 7;             // 0..7

    float4 hv[8], wv[2];
    float acc[4][4] = {};

    // prologue: load chunk 0 into regs
    {
        const int k0 = kbase;
#pragma unroll
        for (int r = 0; r < 8; ++r) {
            int b = hb + r * 8;
            hv[r] = *(const float4*)(h_in + (size_t)b * 1024 + k0 + kq * 4);
        }
#pragma unroll
        for (int r = 0; r < 2; ++r) {
            int row = hb + r * 8;
            int g = row >> 2, jj = row & 3;
            wv[r] = *(const float4*)(W_hh + (size_t)(g * 1024 + j0 + jj) * 1024 + k0 + kq * 4);
        }
    }
    for (int ch = 0; ch < 8; ++ch) {
        // write staged regs to this wave's LDS slice
#pragma unroll
        for (int r = 0; r < 8; ++r) {
            int b = hb + r * 8;
            hs[kg][kq * 4 + 0][b] = hv[r].x; hs[kg][kq * 4 + 1][b] = hv[r].y;
            hs[kg][kq * 4 + 2][b] = hv[r].z; hs[kg][kq * 4 + 3][b] = hv[r].w;
        }
#pragma unroll
        for (int r = 0; r < 2; ++r) {
            int row = hb + r * 8;
            wsm[kg][kq * 4 + 0][row] = wv[r].x; wsm[kg][kq * 4 + 1][row] = wv[r].y;
            wsm[kg][kq * 4 + 2][row] = wv[r].z; wsm[kg][kq * 4 + 3][row] = wv[r].w;
        }
        // prefetch next chunk (hides HBM/L2 latency under compute)
        if (ch < 7) {
            const int k0 = kbase + (ch + 1) * 32;
#pragma unroll
            for (int r = 0; r < 8; ++r) {
                int b = hb + r * 8;
                hv[r] = *(const float4*)(h_in + (size_t)b * 1024 + k0 + kq * 4);
            }
#pragma unroll
            for (int r = 0; r < 2; ++r) {
                int row = hb + r * 8;
                int g = row >> 2, jj = row & 3;
                wv[r] = *(const float4*)(W_hh + (size_t)(g * 1024 + j0 + jj) * 1024 + k0 + kq * 4);
            }
        }
        // compute current chunk (wave-local LDS; no barrier needed)
#pragma unroll
        for (int kk = 0; kk < 32; ++kk) {
            float4 h4 = *(const float4*)&hs[kg][kk][tc * 4];
            float4 w4 = *(const float4*)&wsm[kg][kk][tr * 4];
            float hh[4] = {h4.x, h4.y, h4.z, h4.w};
            float ww[4] = {w4.x, w4.y, w4.z, w4.w};
#pragma unroll
            for (int i = 0; i < 4; ++i)
#pragma unroll
                for (int j = 0; j < 4; ++j)
                    acc[i][j] += ww[i] * hh[j];
        }
    }
#pragma unroll
    for (int i = 0; i < 4; ++i)
#pragma unroll
        for (int j = 0; j < 4; ++j)
            red[kg][(tr * 4 + i) * 64 + tc * 4 + j] = acc[i][j];
    __syncthreads();

    // epilogue: thread -> (b, jj); xgt read is coalesced (b contiguous)
    const int b = tid & 63, jj = tid >> 6;
    float gate[4];
#pragma unroll
    for (int g = 0; g < 4; ++g) {
        int r = g * 4 + jj;
        float s = red[0][r * 64 + b] + red[1][r * 64 + b] + red[2][r * 64 + b] + red[3][r * 64 + b];
        gate[g] = s + xgt[(size_t)t * 262144 + (size_t)(g * 1024 + j0 + jj) * 64 + b];
    }
    float ii = sigmoidf_(gate[0]);
    float ff = sigmoidf_(gate[1]);
    float gg = tanhf(gate[2]);
    float oo = sigmoidf_(gate[3]);
    size_t ci = (size_t)b * 1024 + j0 + jj;
    float cn = ff * c[ci] + ii * gg;
    float hn = oo * tanhf(cn);
    c[ci] = cn;
    h_out[ci] = hn;
    lstm16[((size_t)b * 128 + t) * 1024 + j0 + jj] = f2bf(hn);
}

// ---------------------------------------------------------------------------
// fp32 GEMM C = A @ B^T (for scores), batched via blockIdx.z.
// ---------------------------------------------------------------------------
template <int BM, int BN, int TM, int TN>
__global__ __launch_bounds__(256) void gemm_bt(
    const float* __restrict__ A, const float* __restrict__ Bm, float* __restrict__ C,
    int M, int N, int K, long sA, long sB, long sC)
{
    constexpr int BK = 16;
    __shared__ float As[BK][BM + 1];
    __shared__ float Bs[BK][BN + 1];
    const int z = blockIdx.z;
    A += (long)z * sA; Bm += (long)z * sB; C += (long)z * sC;
    const int bm = blockIdx.y * BM, bn = blockIdx.x * BN;
    const int tid = threadIdx.x;
    constexpr int TC = BN / TN;
    const int tc = tid % TC, tr = tid / TC;
    float acc[TM][TN] = {};
    for (int k0 = 0; k0 < K; k0 += BK) {
        for (int i = tid; i < BM * 4; i += 256) {
            int m = i >> 2, k4 = (i & 3) << 2;
            float4 v = *(const float4*)(A + (long)(bm + m) * K + k0 + k4);
            As[k4][m] = v.x; As[k4 + 1][m] = v.y; As[k4 + 2][m] = v.z; As[k4 + 3][m] = v.w;
        }
        for (int i = tid; i < BN * 4; i += 256) {
            int n = i >> 2, k4 = (i & 3) << 2;
            float4 v = *(const float4*)(Bm + (long)(bn + n) * K + k0 + k4);
            Bs[k4][n] = v.x; Bs[k4 + 1][n] = v.y; Bs[k4 + 2][n] = v.z; Bs[k4 + 3][n] = v.w;
        }
        __syncthreads();
#pragma unroll
        for (int kk = 0; kk < BK; ++kk) {
            float a[TM], b[TN];
#pragma unroll
            for (int i = 0; i < TM; i++) a[i] = As[kk][tr * TM + i];
#pragma unroll
            for (int j = 0; j < TN; j++) b[j] = Bs[kk][tc * TN + j];
#pragma unroll
            for (int i = 0; i < TM; i++)
#pragma unroll
                for (int j = 0; j < TN; j++) acc[i][j] += a[i] * b[j];
        }
        __syncthreads();
    }
#pragma unroll
    for (int i = 0; i < TM; i++) {
        int m = bm + tr * TM + i;
#pragma unroll
        for (int j = 0; j < TN; j++) {
            int n = bn + tc * TN + j;
            C[(long)m * N + n] = acc[i][j];
        }
    }
}

// ---------------------------------------------------------------------------
// fp32 GEMM C = A @ B (B row-major [K,N]) — context = attn @ ctx; OT output.
// ---------------------------------------------------------------------------
template <int BM, int BN, int TM, int TN, typename OT>
__global__ __launch_bounds__(256) void gemm_bn(
    const float* __restrict__ A, const float* __restrict__ Bm, OT* __restrict__ C,
    int M, int N, int K, long sA, long sB, long sC)
{
    constexpr int BK = 16;
    __shared__ float As[BK][BM + 1];
    __shared__ float Bs[BK][BN + 1];
    const int z = blockIdx.z;
    A += (long)z * sA; Bm += (long)z * sB; C += (long)z * sC;
    const int bm = blockIdx.y * BM, bn = blockIdx.x * BN;
    const int tid = threadIdx.x;
    constexpr int TC = BN / TN;
    const int tc = tid % TC, tr = tid / TC;
    float acc[TM][TN] = {};
    for (int k0 = 0; k0 < K; k0 += BK) {
        for (int i = tid; i < BM * 4; i += 256) {
            int m = i >> 2, k4 = (i & 3) << 2;
            float4 v = *(const float4*)(A + (long)(bm + m) * K + k0 + k4);
            As[k4][m] = v.x; As[k4 + 1][m] = v.y; As[k4 + 2][m] = v.z; As[k4 + 3][m] = v.w;
        }
        for (int i = tid; i < BK * (BN / 4); i += 256) {
            int k = i / (BN / 4), n4 = (i % (BN / 4)) * 4;
            float4 v = *(const float4*)(Bm + (long)(k0 + k) * N + bn + n4);
            Bs[k][n4] = v.x; Bs[k][n4 + 1] = v.y; Bs[k][n4 + 2] = v.z; Bs[k][n4 + 3] = v.w;
        }
        __syncthreads();
#pragma unroll
        for (int kk = 0; kk < BK; ++kk) {
            float a[TM], b[TN];
#pragma unroll
            for (int i = 0; i < TM; i++) a[i] = As[kk][tr * TM + i];
#pragma unroll
            for (int j = 0; j < TN; j++) b[j] = Bs[kk][tc * TN + j];
#pragma unroll
            for (int i = 0; i < TM; i++)
#pragma unroll
                for (int j = 0; j < TN; j++) acc[i][j] += a[i] * b[j];
        }
        __syncthreads();
    }
#pragma unroll
    for (int i = 0; i < TM; i++) {
        int m = bm + tr * TM + i;
#pragma unroll
        for (int j = 0; j < TN; j++) {
            int n = bn + tc * TN + j;
            stout(&C[(long)m * N + n], acc[i][j]);
        }
    }
}

// ---------------------------------------------------------------------------
// Masked softmax over S=256, in place. One block per (b,t) row.
// ---------------------------------------------------------------------------
__global__ __launch_bounds__(256) void softmax_mask(
    float* __restrict__ attn, const int* __restrict__ src_len)
{
    __shared__ float red[4];
    const int b = blockIdx.y, t = blockIdx.x, s = threadIdx.x;
    float* row = attn + ((long)b * TT + t) * SS;
    const int L = src_len[b];
    float v = (s < L) ? row[s] : -INFINITY;
    float m = v;
#pragma unroll
    for (int o = 32; o >= 1; o >>= 1) m = fmaxf(m, __shfl_xor(m, o));
    if ((s & 63) == 0) red[s >> 6] = m;
    __syncthreads();
    m = fmaxf(fmaxf(red[0], red[1]), fmaxf(red[2], red[3]));
    __syncthreads();
    float e = (s < L) ? expf(v - m) : 0.0f;
    float sum = e;
#pragma unroll
    for (int o = 32; o >= 1; o >>= 1) sum += __shfl_xor(sum, o);
    if ((s & 63) == 0) red[s >> 6] = sum;
    __syncthreads();
    sum = red[0] + red[1] + red[2] + red[3];
    row[s] = e / sum;
}

// ---------------------------------------------------------------------------
extern "C" void kernel_launch(void* const* d_in, const int* in_sizes, int n_in,
                              void* d_out, int out_size, void* d_ws, size_t ws_size,
                              hipStream_t stream)
{
    const float* trg_emb = (const float*)d_in[0];
    const float* h0      = (const float*)d_in[1];
    const float* c0      = (const float*)d_in[2];
    const float* ctx     = (const float*)d_in[3];
    const int*   src_len = (const int*)d_in[4];
    const float* W_ih    = (const float*)d_in[5];
    const float* W_hh    = (const float*)d_in[6];
    const float* b_ih    = (const float*)d_in[7];
    const float* b_hh    = (const float*)d_in[8];
    const float* W_in    = (const float*)d_in[9];
    const float* W_out   = (const float*)d_in[10];

    float* out = (float*)d_out;
    float* h_tilde = out;                          // [B,T,H]
    float* hT = out + (size_t)BB * TT * HHH;       // [1,B,H]
    float* cT = hT + (size_t)BB * HHH;             // [1,B,H] — running c

    char* w = (char*)d_ws;
    auto take = [&](size_t bytes) { void* p = w; w += (bytes + 255) & ~(size_t)255; return p; };
    u16* trg16  = (u16*)take(8388608ull * 2);
    u16* Wih16  = (u16*)take(4194304ull * 2);
    u16* Win16  = (u16*)take(1048576ull * 2);
    u16* Wout16 = (u16*)take(2097152ull * 2);
    u16* lstm16 = (u16*)take(8388608ull * 2);
    float* hb0  = (float*)take(65536ull * 4);
    float* hb1  = (float*)take(65536ull * 4);
    char* regionB = w;
    float* xgt = (float*)take(33554432ull * 4);    // [t][4H][B] fp32, bias folded
    // region C aliases region B (xgt dead after the scan):
    float* q        = (float*)regionB;                          // 33.5 MB
    float* attn     = (float*)(regionB + 33554432ull);          // 8.4 MB
    u16*   ctxout16 = (u16*)(regionB + 41943040ull);            // 16.8 MB

    // weight / input conversions (every call — deterministic)
    f32_to_bf16<<<4096, 256, 0, stream>>>(trg_emb, trg16, 8388608);
    f32_to_bf16<<<2048, 256, 0, stream>>>(W_ih, Wih16, 4194304);
    f32_to_bf16<<<512, 256, 0, stream>>>(W_in, Win16, 1048576);
    f32_to_bf16<<<1024, 256, 0, stream>>>(W_out, Wout16, 2097152);

    hipMemcpyAsync(cT, c0, (size_t)BB * HHH * 4, hipMemcpyDeviceToDevice, stream);
    hipMemcpyAsync(hb0, h0, (size_t)BB * HHH * 4, hipMemcpyDeviceToDevice, stream);

    // x_gates = trg_emb @ W_ih^T + (b_ih + b_hh), fused transpose to
    // xgt[t][4H][B] fp32 (single rounding point: bf16 MFMA inputs only)
    gemm_mfma_bt<false, true, float><<<dim3(32, 64), 256, 0, stream>>>(
        trg16, trg16, Wih16, xgt, 8192, 4096, 1024, 1024, b_ih, b_hh);

    // LSTM scan: 128 sequential steps (h ping-pong, c in place in cT)
    for (int t = 0; t < TT; ++t) {
        const float* hi = (t & 1) ? hb1 : hb0;
        float* ho = (t & 1) ? hb0 : hb1;
        lstm_step2<<<256, 256, 0, stream>>>(xgt, W_hh, hi, ho, cT, lstm16, t);
    }
    hipMemcpyAsync(hT, hb0, (size_t)BB * HHH * 4, hipMemcpyDeviceToDevice, stream);

    // q = lstm_out @ W_in^T (bf16 MFMA, fp32 out)
    gemm_mfma_bt<false, false, float><<<dim3(8, 64), 256, 0, stream>>>(
        lstm16, lstm16, Win16, q, 8192, 1024, 1024, 1024, nullptr, nullptr);

    // scores[b] = q[b] @ ctx[b]^T (fp32)
    gemm_bt<64, 64, 4, 4><<<dim3(4, 2, 64), 256, 0, stream>>>(
        q, ctx, attn, TT, SS, HHH,
        (long)TT * HHH, (long)SS * HHH, (long)TT * SS);

    softmax_mask<<<dim3(TT, BB, 1), 256, 0, stream>>>(attn, src_len);

    // context[b] = attn[b] @ ctx[b] (fp32 compute, bf16 out)
    gemm_bn<64, 64, 4, 4, u16><<<dim3(16, 2, 64), 256, 0, stream>>>(
        attn, ctx, ctxout16, TT, HHH, SS,
        (long)TT * SS, (long)SS * HHH, (long)TT * HHH);

    // h_tilde = tanh([context, lstm_out] @ W_out^T) (bf16 MFMA, fp32 out)
    gemm_mfma_bt<true, false, float><<<dim3(8, 64), 256, 0, stream>>>(
        ctxout16, lstm16, Wout16, h_tilde, 8192, 1024, 2048, 1024, nullptr, nullptr);
}